// Round 10
// baseline (624.097 us; speedup 1.0000x reference)
//
#include <hip/hip_runtime.h>
#include <math.h>

#define NN    10000
#define SSS   4
#define LL    8
#define HH    128
#define NSEQ  40000
#define SUBN  100
#define ORIGF 64
#define MA    16
#define TA    512

typedef unsigned short u16;
typedef short bf16x8 __attribute__((ext_vector_type(8)));
typedef float f32x4 __attribute__((ext_vector_type(4)));

// ---- LDS layout (bytes), total < 64 KB (occupancy hypothesis) ----
#define WL_OFF    0        // u16[3072]  staged Wih_w (bf16)
#define BWRZ_OFF  6144     // f32[256]   bihW+bhhW (r,z)
#define BWIN_OFF  7168     // f32[128]   bihW n
#define BWHN_OFF  7680     // f32[128]   bhhW n
#define BMRZ_OFF  8192     // f32[256]   bih+bhh (r,z)
#define BMIN_OFF  9216     // f32[128]   bih n
#define BMHN_OFF  9728     // f32[128]   bhh n
#define SH_OFF    10240    // f32[16][132] fp32 master h (stride-padded: 4-way -> 2-way banks)
#define SH_STR    132
#define HB_OFF    18688    // u16[2][16*136] bf16 h, double-buffered
#define HBBUF     2176
#define HB_STR    136
#define XB_OFF    27392    // u16[128][136] y_walk (t*16+m rows)
#define XB_STR    136
#define SWF_OFF   62208    // int[16*8]
#define SUF_OFF   62720    // int[16*8]
#define SCNT_OFF  63232    // int[16]
#define SANY_OFF  63296    // int
#define LDS_TOTAL 63312

// ws: ws[0..3] accum; byte 64: bf16 weights (whhw | whh | wih)
#define WB_BYTE_OFF 64
#define W_HHW_N 49152
#define W_HH_N  49152
#define W_IH_N  98304
#define W_TOTAL (W_HHW_N + W_HH_N + W_IH_N)

__device__ __forceinline__ float bf2f(u16 u) {
  return __uint_as_float(((unsigned)u) << 16);
}
__device__ __forceinline__ u16 f2bf(float f) {
  unsigned u = __float_as_uint(f);
  u += 0x7fffu + ((u >> 16) & 1u);   // RNE
  return (u16)(u >> 16);
}
__device__ __forceinline__ bf16x8 pack8(float4 v0, float4 v1) {
  bf16x8 r;
  r[0] = (short)f2bf(v0.x); r[1] = (short)f2bf(v0.y);
  r[2] = (short)f2bf(v0.z); r[3] = (short)f2bf(v0.w);
  r[4] = (short)f2bf(v1.x); r[5] = (short)f2bf(v1.y);
  r[6] = (short)f2bf(v1.z); r[7] = (short)f2bf(v1.w);
  return r;
}
__device__ __forceinline__ float sigmoidf_(float x) { return 1.f / (1.f + __expf(-x)); }
__device__ __forceinline__ float tanhf_(float x) {   // NaN-free fast tanh
  const float e = __expf(2.f * x);
  return 1.f - 2.f / (e + 1.f);
}
__device__ __forceinline__ float softplusf_(float x) {
  return fmaxf(x, 0.f) + log1pf(__expf(-fabsf(x)));
}

__global__ void k_zero(float* ws) {
  if (threadIdx.x < 4) ws[threadIdx.x] = 0.f;
}

__global__ void k_prep(const float* __restrict__ whhw, const float* __restrict__ whh,
                       const float* __restrict__ wih, float* __restrict__ ws) {
  const int i = blockIdx.x * 256 + threadIdx.x;
  u16* wb = (u16*)((char*)ws + WB_BYTE_OFF);
  if (i < W_HHW_N)                wb[i] = f2bf(whhw[i]);
  else if (i < W_HHW_N + W_HH_N)  wb[i] = f2bf(whh[i - W_HHW_N]);
  else                            wb[i] = f2bf(wih[i - W_HHW_N - W_HH_N]);
}

__global__ __launch_bounds__(TA, 2) void k_rum(
    const float* __restrict__ hfeat, const float* __restrict__ y0,
    const float* __restrict__ WihW,  const float* __restrict__ bihW,
    const float* __restrict__ bhhW,
    const float* __restrict__ bih,   const float* __restrict__ bhh,
    const float* __restrict__ W_ss,  const float* __restrict__ b_ss,
    const int* __restrict__ walks,   const int* __restrict__ idxs,
    float* __restrict__ out, float* __restrict__ ws)
{
  extern __shared__ char sm[];
  u16*   WLb  = (u16*)(sm + WL_OFF);
  float* bwrz = (float*)(sm + BWRZ_OFF);
  float* bwin = (float*)(sm + BWIN_OFF);
  float* bwhn = (float*)(sm + BWHN_OFF);
  float* bmrz = (float*)(sm + BMRZ_OFF);
  float* bmin = (float*)(sm + BMIN_OFF);
  float* bmhn = (float*)(sm + BMHN_OFF);
  float* sh   = (float*)(sm + SH_OFF);
  u16*   hb   = (u16*)(sm + HB_OFF);      // [2][HBBUF]
  u16*   xb   = (u16*)(sm + XB_OFF);
  int*   swf  = (int*)(sm + SWF_OFF);
  int*   suf  = (int*)(sm + SUF_OFF);
  int*   scnt = (int*)(sm + SCNT_OFF);
  int*   sany = (int*)(sm + SANY_OFF);

  const u16* wb     = (const u16*)((const char*)ws + WB_BYTE_OFF);
  const u16* whhw_b = wb;
  const u16* whh_b  = wb + W_HHW_N;
  const u16* wih_b  = wb + W_HHW_N + W_HH_N;

  const int tid = threadIdx.x;
  const int lane = tid & 63, c = lane & 15, qd = lane >> 4;
  const int wv = tid >> 6;                  // 0..7: owns gate-tiles {wv, 8+wv, 16+wv}
  const int i0 = wv * 16 + c;               // this lane's hidden index
  const int q0 = blockIdx.x * MA;

  // ---- phase 0: staging + walk preprocessing ----
  if (tid < MA) {
    const int m = tid;
    scnt[m] = 0;
    const int q = q0 + m;
    int w[LL];
    #pragma unroll
    for (int l = 0; l < LL; ++l) w[l] = walks[q * LL + l];
    #pragma unroll
    for (int l = 0; l < LL; ++l) {
      int u = l;
      #pragma unroll
      for (int l2 = LL - 1; l2 >= 0; --l2) if (w[l2] == w[l]) u = l2;
      swf[m * LL + (LL - 1 - l)] = w[l];
      suf[m * LL + (LL - 1 - l)] = u;
    }
  }
  if (tid == 0) *sany = 0;
  for (int idx = tid; idx < 3072; idx += TA) WLb[idx] = f2bf(WihW[idx]);
  if (tid < 256) { bwrz[tid] = bihW[tid] + bhhW[tid]; bmrz[tid] = bih[tid] + bhh[tid]; }
  if (tid < 128) {
    bwin[tid] = bihW[256 + tid]; bwhn[tid] = bhhW[256 + tid];
    bmin[tid] = bih[256 + tid];  bmhn[tid] = bhh[256 + tid];
  }
  for (int idx = tid; idx < MA * SH_STR; idx += TA) sh[idx] = 0.f;
  for (int idx = tid; idx < HBBUF; idx += TA) hb[idx] = 0;
  __syncthreads();

  for (int p = tid; p < MA * SUBN; p += TA) {
    const int m = p / SUBN, i = p % SUBN;
    if (idxs[i] == (q0 + m) % NN) { atomicAdd(&scnt[m], 1); *sany = 1; }
  }

  // ---- walk GRU: wave-local activation, 1 barrier/step ----
  {
    bf16x8 BA[3][4];
    #pragma unroll
    for (int tl = 0; tl < 3; ++tl) {
      const int row = (tl * 8 + wv) * 16 + c;
      #pragma unroll
      for (int k = 0; k < 4; ++k)
        BA[tl][k] = *(const bf16x8*)(whhw_b + row * HH + k * 32 + qd * 8);
    }
    #pragma unroll
    for (int t = 0; t < LL; ++t) {
      const u16* hbc = hb + (t & 1) * HBBUF;
      u16*       hbn = hb + ((t + 1) & 1) * HBBUF;
      bf16x8 a[4];
      #pragma unroll
      for (int k = 0; k < 4; ++k)
        a[k] = *(const bf16x8*)(hbc + c * HB_STR + k * 32 + qd * 8);
      f32x4 D[3];
      #pragma unroll
      for (int tl = 0; tl < 3; ++tl) {
        f32x4 d = {0.f, 0.f, 0.f, 0.f};
        #pragma unroll
        for (int k = 0; k < 4; ++k)
          d = __builtin_amdgcn_mfma_f32_16x16x32_bf16(a[k], BA[tl][k], d, 0, 0, 0);
        D[tl] = d;
      }
      #pragma unroll
      for (int reg = 0; reg < 4; ++reg) {
        const int m = qd * 4 + reg;
        const int u = suf[m * LL + t];
        const float r = sigmoidf_(bf2f(WLb[i0 * LL + u]) + D[0][reg] + bwrz[i0]);
        const float z = sigmoidf_(bf2f(WLb[(HH + i0) * LL + u]) + D[1][reg] + bwrz[HH + i0]);
        const float n = tanhf_(bf2f(WLb[(2 * HH + i0) * LL + u]) + bwin[i0]
                               + r * (D[2][reg] + bwhn[i0]));
        const float hn = (1.f - z) * n + z * sh[m * SH_STR + i0];
        sh[m * SH_STR + i0] = hn;
        const u16 hv = f2bf(hn);
        hbn[m * HB_STR + i0] = hv;
        xb[(t * 16 + m) * XB_STR + i0] = hv;
      }
      __syncthreads();
    }
  }

  // ---- load main-phase weight fragments ----
  bf16x8 BW[3][8], BC[3][4];
  #pragma unroll
  for (int tl = 0; tl < 3; ++tl) {
    const int row = (tl * 8 + wv) * 16 + c;
    #pragma unroll
    for (int kk = 0; kk < 8; ++kk)
      BW[tl][kk] = *(const bf16x8*)(wih_b + row * 256 + kk * 32 + qd * 8);
    #pragma unroll
    for (int k = 0; k < 4; ++k)
      BC[tl][k] = *(const bf16x8*)(whh_b + row * HH + k * 32 + qd * 8);
  }

  // input-gate pre-activations for step t: computed one step ahead, registers only
  f32x4 gi[2][3];
  auto doB = [&](int t, f32x4* g) {
    bf16x8 ah[4], ay[4];
    const int node = swf[c * LL + t];
    #pragma unroll
    for (int k = 0; k < 4; ++k) {
      const float* hp = hfeat + (size_t)node * HH + k * 32 + qd * 8;
      ah[k] = pack8(*(const float4*)hp, *(const float4*)(hp + 4));
      ay[k] = *(const bf16x8*)(xb + (t * 16 + c) * XB_STR + k * 32 + qd * 8);
    }
    #pragma unroll
    for (int tl = 0; tl < 3; ++tl) {
      f32x4 d = {0.f, 0.f, 0.f, 0.f};
      #pragma unroll
      for (int k = 0; k < 4; ++k)
        d = __builtin_amdgcn_mfma_f32_16x16x32_bf16(ah[k], BW[tl][k], d, 0, 0, 0);
      #pragma unroll
      for (int k = 0; k < 4; ++k)
        d = __builtin_amdgcn_mfma_f32_16x16x32_bf16(ay[k], BW[tl][4 + k], d, 0, 0, 0);
      g[tl] = d;
    }
  };
  doB(0, gi[0]);

  float pAcc = 0.f, pBcc = 0.f, pScc = 0.f;

  // ---- main GRU: 1 barrier/step (+1 in the ~15% loss blocks) ----
  #pragma unroll
  for (int t = 0; t < LL; ++t) {
    const u16* hbc = hb + (t & 1) * HBBUF;
    u16*       hbn = hb + ((t + 1) & 1) * HBBUF;
    bf16x8 a[4];
    #pragma unroll
    for (int k = 0; k < 4; ++k)
      a[k] = *(const bf16x8*)(hbc + c * HB_STR + k * 32 + qd * 8);
    f32x4 D[3];
    #pragma unroll
    for (int tl = 0; tl < 3; ++tl) {
      f32x4 d = {0.f, 0.f, 0.f, 0.f};
      #pragma unroll
      for (int k = 0; k < 4; ++k)
        d = __builtin_amdgcn_mfma_f32_16x16x32_bf16(a[k], BC[tl][k], d, 0, 0, 0);
      D[tl] = d;
    }
    const f32x4* gp = gi[t & 1];
    #pragma unroll
    for (int reg = 0; reg < 4; ++reg) {
      const int m = qd * 4 + reg;
      const float r = sigmoidf_(D[0][reg] + gp[0][reg] + bmrz[i0]);
      const float z = sigmoidf_(D[1][reg] + gp[1][reg] + bmrz[HH + i0]);
      const float n = tanhf_(gp[2][reg] + bmin[i0] + r * (D[2][reg] + bmhn[i0]));
      const float hn = (1.f - z) * n + z * sh[m * SH_STR + i0];
      sh[m * SH_STR + i0] = hn;
      hbn[m * HB_STR + i0] = f2bf(hn);
    }

    if (t < LL - 1 && *sany) {          // block-uniform branch
      __syncthreads();                  // sh rows complete for cross-wave read
      for (int idx = tid; idx < MA * ORIGF; idx += TA) {
        const int m = idx >> 6, o = idx & 63;
        const int cnt = scnt[m];
        if (cnt > 0) {
          const float* wr = W_ss + o * HH;
          float acc = b_ss[o];
          #pragma unroll 1
          for (int kc = 0; kc < HH; kc += 8) {
            const float4 wa = *(const float4*)(wr + kc);
            const float4 wb4 = *(const float4*)(wr + kc + 4);
            const float4 xa = *(const float4*)(&sh[m * SH_STR + kc]);
            const float4 xv = *(const float4*)(&sh[m * SH_STR + kc + 4]);
            acc = fmaf(wa.x, xa.x, acc); acc = fmaf(wa.y, xa.y, acc);
            acc = fmaf(wa.z, xa.z, acc); acc = fmaf(wa.w, xa.w, acc);
            acc = fmaf(wb4.x, xv.x, acc); acc = fmaf(wb4.y, xv.y, acc);
            acc = fmaf(wb4.z, xv.z, acc); acc = fmaf(wb4.w, xv.w, acc);
          }
          const float fc = (float)cnt;
          const float yt = y0[(size_t)swf[m * LL + t + 1] * ORIGF + o];
          pAcc += fc * yt * softplusf_(-acc);
          pBcc += fc * (1.f - yt) * softplusf_(acc);
          pScc += fc * yt;
        }
      }
    }
    __syncthreads();
    if (t < LL - 1) doB(t + 1, gi[(t + 1) & 1]);
  }

  // ---- epilogue: hT + loss reduction ----
  for (int idx = tid; idx < MA * HH; idx += TA)
    out[(size_t)(q0 + (idx >> 7)) * HH + (idx & 127)] = sh[(idx >> 7) * SH_STR + (idx & 127)];

  if (*sany) {
    float* red = (float*)(sm + WL_OFF);   // WL dead after walk phase (6144 B = 3*TA floats)
    red[tid] = pAcc; red[TA + tid] = pBcc; red[2 * TA + tid] = pScc;
    __syncthreads();
    if (wv == 0) {
      float a = 0.f, b = 0.f, s = 0.f;
      for (int k2 = lane; k2 < TA; k2 += 64) {
        a += red[k2]; b += red[TA + k2]; s += red[2 * TA + k2];
      }
      #pragma unroll
      for (int off = 32; off > 0; off >>= 1) {
        a += __shfl_down(a, off); b += __shfl_down(b, off); s += __shfl_down(s, off);
      }
      if (lane == 0) {
        atomicAdd(&ws[1], a); atomicAdd(&ws[2], b); atomicAdd(&ws[3], s);
      }
    }
  }
}

__global__ void k_final(const float* __restrict__ ws, float* __restrict__ out) {
  if (threadIdx.x == 0) {
    const float cnt = (float)(SSS * SUBN * (LL - 1) * ORIGF);  // 179200
    const float pos_w = cnt / ws[3];
    const float loss = (pos_w * ws[1] + ws[2]) / cnt;
    out[NSEQ * HH] = loss;
  }
}

extern "C" void kernel_launch(void* const* d_in, const int* in_sizes, int n_in,
                              void* d_out, int out_size, void* d_ws, size_t ws_size,
                              hipStream_t stream) {
  const float* hfeat = (const float*)d_in[0];
  const float* y0    = (const float*)d_in[1];
  const float* Wih_w = (const float*)d_in[2];
  const float* Whh_w = (const float*)d_in[3];
  const float* bih_w = (const float*)d_in[4];
  const float* bhh_w = (const float*)d_in[5];
  const float* Wih   = (const float*)d_in[6];
  const float* Whh   = (const float*)d_in[7];
  const float* bih   = (const float*)d_in[8];
  const float* bhh   = (const float*)d_in[9];
  const float* W_ss  = (const float*)d_in[10];
  const float* b_ss  = (const float*)d_in[11];
  const int* walks = (const int*)d_in[12];
  const int* idxs  = (const int*)d_in[13];
  float* out = (float*)d_out;
  float* ws = (float*)d_ws;

  (void)hipFuncSetAttribute((const void*)k_rum,
                            hipFuncAttributeMaxDynamicSharedMemorySize, LDS_TOTAL);

  k_zero<<<1, 64, 0, stream>>>(ws);
  k_prep<<<W_TOTAL / 256, 256, 0, stream>>>(Whh_w, Whh, Wih, ws);

  const int grid = NSEQ / MA;               // 2500, exact
  k_rum<<<grid, TA, LDS_TOTAL, stream>>>(hfeat, y0, Wih_w, bih_w, bhh_w,
                                         bih, bhh, W_ss, b_ss,
                                         walks, idxs, out, ws);

  k_final<<<1, 64, 0, stream>>>(ws, out);
}

// Round 12
// 525.099 us; speedup vs baseline: 1.1885x; 1.1885x over previous
//
#include <hip/hip_runtime.h>
#include <math.h>

#define NN    10000
#define SSS   4
#define LL    8
#define HH    128
#define NSEQ  40000
#define SUBN  100
#define ORIGF 64
#define MA    16
#define TA    512

typedef unsigned short u16;
typedef short bf16x8 __attribute__((ext_vector_type(8)));
typedef float f32x4 __attribute__((ext_vector_type(4)));

// ---- LDS layout (bytes) ----
#define WL_OFF    0        // u16[3072]  staged Wih_w (bf16)
#define BWRZ_OFF  6144     // f32[256]   bihW+bhhW (r,z)
#define BWIN_OFF  7168     // f32[128]   bihW n
#define BWHN_OFF  7680     // f32[128]   bhhW n
#define BMRZ_OFF  8192     // f32[256]   bih+bhh (r,z)
#define BMIN_OFF  9216     // f32[128]   bih n
#define BMHN_OFF  9728     // f32[128]   bhh n
#define SH_OFF    10240    // f32[16][132] fp32 master h
#define SH_STR    132
#define HB_OFF    18688    // u16[2][16*136] bf16 h, double-buffered
#define HBBUF     2176
#define HB_STR    136
#define XB_OFF    27392    // u16[128][136] y_walk (t*16+m rows)
#define XB_STR    136
#define SWF_OFF   62208    // int[16*8]
#define SUF_OFF   62720    // int[16*8]
#define SCNT_OFF  63232    // int[16]
#define SANY_OFF  63296    // int
#define LDS_TOTAL 63312

// ws: ws[0..3] accum; byte 64: bf16 weights (whhw | whh | wih) then bf16 hfeat
#define WB_BYTE_OFF 64
#define W_HHW_N 49152
#define W_HH_N  49152
#define W_IH_N  98304
#define W_TOTAL (W_HHW_N + W_HH_N + W_IH_N)
#define WS_NEED ((size_t)WB_BYTE_OFF + (size_t)W_TOTAL * 2 + (size_t)NN * HH * 2)

__device__ __forceinline__ float bf2f(u16 u) {
  return __uint_as_float(((unsigned)u) << 16);
}
__device__ __forceinline__ u16 f2bf(float f) {
  unsigned u = __float_as_uint(f);
  u += 0x7fffu + ((u >> 16) & 1u);   // RNE
  return (u16)(u >> 16);
}
__device__ __forceinline__ bf16x8 pack8(float4 v0, float4 v1) {
  bf16x8 r;
  r[0] = (short)f2bf(v0.x); r[1] = (short)f2bf(v0.y);
  r[2] = (short)f2bf(v0.z); r[3] = (short)f2bf(v0.w);
  r[4] = (short)f2bf(v1.x); r[5] = (short)f2bf(v1.y);
  r[6] = (short)f2bf(v1.z); r[7] = (short)f2bf(v1.w);
  return r;
}
__device__ __forceinline__ float sigmoidf_(float x) { return 1.f / (1.f + __expf(-x)); }
__device__ __forceinline__ float tanhf_(float x) {   // NaN-free fast tanh
  const float e = __expf(2.f * x);
  return 1.f - 2.f / (e + 1.f);
}
__device__ __forceinline__ float softplusf_(float x) {
  return fmaxf(x, 0.f) + log1pf(__expf(-fabsf(x)));
}

__global__ void k_zero(float* ws) {
  if (threadIdx.x < 4) ws[threadIdx.x] = 0.f;
}

__global__ void k_prep(const float* __restrict__ whhw, const float* __restrict__ whh,
                       const float* __restrict__ wih, float* __restrict__ ws) {
  const int i = blockIdx.x * 256 + threadIdx.x;
  u16* wb = (u16*)((char*)ws + WB_BYTE_OFF);
  if (i < W_HHW_N)                wb[i] = f2bf(whhw[i]);
  else if (i < W_HHW_N + W_HH_N)  wb[i] = f2bf(whh[i - W_HHW_N]);
  else                            wb[i] = f2bf(wih[i - W_HHW_N - W_HH_N]);
}

__global__ void k_prep_h(const float* __restrict__ h, float* __restrict__ ws) {
  const int i = blockIdx.x * 256 + threadIdx.x;       // grid exact: NN*HH/256
  u16* hb16 = (u16*)((char*)ws + WB_BYTE_OFF) + W_TOTAL;
  hb16[i] = f2bf(h[i]);
}

template<bool BF>
__global__ __launch_bounds__(TA, 2) void k_rum(
    const float* __restrict__ hfeat, const float* __restrict__ y0,
    const float* __restrict__ WihW,  const float* __restrict__ bihW,
    const float* __restrict__ bhhW,
    const float* __restrict__ bih,   const float* __restrict__ bhh,
    const float* __restrict__ W_ss,  const float* __restrict__ b_ss,
    const int* __restrict__ walks,   const int* __restrict__ idxs,
    float* __restrict__ out, float* __restrict__ ws)
{
  extern __shared__ char sm[];
  u16*   WLb  = (u16*)(sm + WL_OFF);
  float* bwrz = (float*)(sm + BWRZ_OFF);
  float* bwin = (float*)(sm + BWIN_OFF);
  float* bwhn = (float*)(sm + BWHN_OFF);
  float* bmrz = (float*)(sm + BMRZ_OFF);
  float* bmin = (float*)(sm + BMIN_OFF);
  float* bmhn = (float*)(sm + BMHN_OFF);
  float* sh   = (float*)(sm + SH_OFF);
  u16*   hb   = (u16*)(sm + HB_OFF);      // [2][HBBUF]
  u16*   xb   = (u16*)(sm + XB_OFF);
  int*   swf  = (int*)(sm + SWF_OFF);
  int*   suf  = (int*)(sm + SUF_OFF);
  int*   scnt = (int*)(sm + SCNT_OFF);
  int*   sany = (int*)(sm + SANY_OFF);

  const u16* wb     = (const u16*)((const char*)ws + WB_BYTE_OFF);
  const u16* whhw_b = wb;
  const u16* whh_b  = wb + W_HHW_N;
  const u16* wih_b  = wb + W_HHW_N + W_HH_N;
  const u16* hf16   = wb + W_TOTAL;       // only valid when BF

  const int tid = threadIdx.x;
  const int lane = tid & 63, c = lane & 15, qd = lane >> 4;
  const int wv = tid >> 6;                  // 0..7: owns gate-tiles {wv, 8+wv, 16+wv}
  const int i0 = wv * 16 + c;               // this lane's hidden index
  const int q0 = blockIdx.x * MA;

  // ---- phase 0 ----
  if (tid < MA) {
    const int m = tid;
    scnt[m] = 0;
    const int q = q0 + m;
    int w[LL];
    #pragma unroll
    for (int l = 0; l < LL; ++l) w[l] = walks[q * LL + l];
    #pragma unroll
    for (int l = 0; l < LL; ++l) {
      int u = l;
      #pragma unroll
      for (int l2 = LL - 1; l2 >= 0; --l2) if (w[l2] == w[l]) u = l2;
      swf[m * LL + (LL - 1 - l)] = w[l];
      suf[m * LL + (LL - 1 - l)] = u;
    }
  }
  if (tid == 0) *sany = 0;
  for (int idx = tid; idx < 3072; idx += TA) WLb[idx] = f2bf(WihW[idx]);
  if (tid < 256) { bwrz[tid] = bihW[tid] + bhhW[tid]; bmrz[tid] = bih[tid] + bhh[tid]; }
  if (tid < 128) {
    bwin[tid] = bihW[256 + tid]; bwhn[tid] = bhhW[256 + tid];
    bmin[tid] = bih[256 + tid];  bmhn[tid] = bhh[256 + tid];
  }
  for (int idx = tid; idx < MA * SH_STR; idx += TA) sh[idx] = 0.f;
  for (int idx = tid; idx < HBBUF; idx += TA) hb[idx] = 0;
  __syncthreads();

  for (int p = tid; p < MA * SUBN; p += TA) {
    const int m = p / SUBN, i = p % SUBN;
    if (idxs[i] == (q0 + m) % NN) { atomicAdd(&scnt[m], 1); *sany = 1; }
  }

  // per-lane invariant biases
  const float bw1 = bwrz[i0], bw2 = bwrz[HH + i0], bw3 = bwin[i0], bw4 = bwhn[i0];
  const float bm1 = bmrz[i0], bm2 = bmrz[HH + i0], bm3 = bmin[i0], bm4 = bmhn[i0];

  // ---- walk GRU: wave-local activation, 1 barrier/step ----
  {
    bf16x8 BA[3][4];
    #pragma unroll
    for (int tl = 0; tl < 3; ++tl) {
      const int row = (tl * 8 + wv) * 16 + c;
      #pragma unroll
      for (int k = 0; k < 4; ++k)
        BA[tl][k] = *(const bf16x8*)(whhw_b + row * HH + k * 32 + qd * 8);
    }
    #pragma unroll
    for (int t = 0; t < LL; ++t) {
      const u16* hbc = hb + (t & 1) * HBBUF;
      u16*       hbn = hb + ((t + 1) & 1) * HBBUF;
      bf16x8 a[4];
      #pragma unroll
      for (int k = 0; k < 4; ++k)
        a[k] = *(const bf16x8*)(hbc + c * HB_STR + k * 32 + qd * 8);
      f32x4 D[3];
      #pragma unroll
      for (int tl = 0; tl < 3; ++tl) {
        f32x4 d = {0.f, 0.f, 0.f, 0.f};
        #pragma unroll
        for (int k = 0; k < 4; ++k)
          d = __builtin_amdgcn_mfma_f32_16x16x32_bf16(a[k], BA[tl][k], d, 0, 0, 0);
        D[tl] = d;
      }
      #pragma unroll
      for (int reg = 0; reg < 4; ++reg) {
        const int m = qd * 4 + reg;
        const int u = suf[m * LL + t];
        const float r = sigmoidf_(bf2f(WLb[i0 * LL + u]) + D[0][reg] + bw1);
        const float z = sigmoidf_(bf2f(WLb[(HH + i0) * LL + u]) + D[1][reg] + bw2);
        const float n = tanhf_(bf2f(WLb[(2 * HH + i0) * LL + u]) + bw3
                               + r * (D[2][reg] + bw4));
        const float hn = (1.f - z) * n + z * sh[m * SH_STR + i0];
        sh[m * SH_STR + i0] = hn;
        const u16 hv = f2bf(hn);
        hbn[m * HB_STR + i0] = hv;
        xb[(t * 16 + m) * XB_STR + i0] = hv;
      }
      __syncthreads();
    }
  }

  const bool anyf = (*sany != 0);          // stable after walk barriers

  // ---- load main-phase weight fragments ----
  bf16x8 BW[3][8], BC[3][4];
  #pragma unroll
  for (int tl = 0; tl < 3; ++tl) {
    const int row = (tl * 8 + wv) * 16 + c;
    #pragma unroll
    for (int kk = 0; kk < 8; ++kk)
      BW[tl][kk] = *(const bf16x8*)(wih_b + row * 256 + kk * 32 + qd * 8);
    #pragma unroll
    for (int k = 0; k < 4; ++k)
      BC[tl][k] = *(const bf16x8*)(whh_b + row * HH + k * 32 + qd * 8);
  }

  // ---- prefetch state for phase B (one step ahead, registers only) ----
  bf16x8 ah2[4], ay2[4];
  float4 ahr[8];                            // raw f32 prefetch when !BF
  auto loadB = [&](int t) {
    const int node = swf[c * LL + t];
    if constexpr (BF) {
      const u16* hp = hf16 + (size_t)node * HH + qd * 8;
      #pragma unroll
      for (int k = 0; k < 4; ++k) ah2[k] = *(const bf16x8*)(hp + k * 32);
    } else {
      const float* hp = hfeat + (size_t)node * HH + qd * 8;
      #pragma unroll
      for (int k = 0; k < 4; ++k) {
        ahr[2 * k]     = *(const float4*)(hp + k * 32);
        ahr[2 * k + 1] = *(const float4*)(hp + k * 32 + 4);
      }
    }
    #pragma unroll
    for (int k = 0; k < 4; ++k)
      ay2[k] = *(const bf16x8*)(xb + (t * 16 + c) * XB_STR + k * 32 + qd * 8);
  };
  f32x4 gi[2][3];
  auto mfmaB = [&](f32x4* g) {
    bf16x8 ah[4];
    if constexpr (BF) {
      #pragma unroll
      for (int k = 0; k < 4; ++k) ah[k] = ah2[k];
    } else {
      #pragma unroll
      for (int k = 0; k < 4; ++k) ah[k] = pack8(ahr[2 * k], ahr[2 * k + 1]);
    }
    #pragma unroll
    for (int tl = 0; tl < 3; ++tl) {
      f32x4 dA = {0.f, 0.f, 0.f, 0.f}, dB = {0.f, 0.f, 0.f, 0.f};
      #pragma unroll
      for (int k = 0; k < 4; ++k) {
        dA = __builtin_amdgcn_mfma_f32_16x16x32_bf16(ah[k], BW[tl][k], dA, 0, 0, 0);
        dB = __builtin_amdgcn_mfma_f32_16x16x32_bf16(ay2[k], BW[tl][4 + k], dB, 0, 0, 0);
      }
      g[tl] = dA + dB;
    }
  };

  loadB(0);
  mfmaB(gi[0]);
  loadB(1);

  float pAcc = 0.f, pBcc = 0.f, pScc = 0.f;

  // ---- main GRU ----
  #pragma unroll
  for (int t = 0; t < LL; ++t) {
    const u16* hbc = hb + (t & 1) * HBBUF;
    u16*       hbn = hb + ((t + 1) & 1) * HBBUF;
    bf16x8 a[4];
    #pragma unroll
    for (int k = 0; k < 4; ++k)
      a[k] = *(const bf16x8*)(hbc + c * HB_STR + k * 32 + qd * 8);
    f32x4 D[3];
    #pragma unroll
    for (int tl = 0; tl < 3; ++tl) {
      f32x4 d = {0.f, 0.f, 0.f, 0.f};
      #pragma unroll
      for (int k = 0; k < 4; ++k)
        d = __builtin_amdgcn_mfma_f32_16x16x32_bf16(a[k], BC[tl][k], d, 0, 0, 0);
      D[tl] = d;
    }
    const f32x4* gp = gi[t & 1];
    #pragma unroll
    for (int reg = 0; reg < 4; ++reg) {
      const int m = qd * 4 + reg;
      const float r = sigmoidf_(D[0][reg] + gp[0][reg] + bm1);
      const float z = sigmoidf_(D[1][reg] + gp[1][reg] + bm2);
      const float n = tanhf_(gp[2][reg] + bm3 + r * (D[2][reg] + bm4));
      const float hn = (1.f - z) * n + z * sh[m * SH_STR + i0];
      sh[m * SH_STR + i0] = hn;
      hbn[m * HB_STR + i0] = f2bf(hn);
    }

    if (t < LL - 1 && anyf) {           // block-uniform branch
      __syncthreads();                  // sh rows complete for cross-wave read
      // MA*ORIGF = 1024 > TA = 512 -> MUST be a strided loop (round-2/11 bug class)
      for (int idx = tid; idx < MA * ORIGF; idx += TA) {
        const int m = idx >> 6, o = idx & 63;
        const int cnt = scnt[m];
        if (cnt > 0) {
          const float* wr = W_ss + o * HH;
          float acc = b_ss[o];
          #pragma unroll 1
          for (int kc = 0; kc < HH; kc += 8) {
            const float4 wa = *(const float4*)(wr + kc);
            const float4 wb4 = *(const float4*)(wr + kc + 4);
            const float4 xa = *(const float4*)(&sh[m * SH_STR + kc]);
            const float4 xv = *(const float4*)(&sh[m * SH_STR + kc + 4]);
            acc = fmaf(wa.x, xa.x, acc); acc = fmaf(wa.y, xa.y, acc);
            acc = fmaf(wa.z, xa.z, acc); acc = fmaf(wa.w, xa.w, acc);
            acc = fmaf(wb4.x, xv.x, acc); acc = fmaf(wb4.y, xv.y, acc);
            acc = fmaf(wb4.z, xv.z, acc); acc = fmaf(wb4.w, xv.w, acc);
          }
          const float fc = (float)cnt;
          const float yt = y0[(size_t)swf[m * LL + t + 1] * ORIGF + o];
          pAcc += fc * yt * softplusf_(-acc);
          pBcc += fc * (1.f - yt) * softplusf_(acc);
          pScc += fc * yt;
        }
      }
    }
    __syncthreads();
    if (t < LL - 1) {
      mfmaB(gi[(t + 1) & 1]);           // consume prefetched operands
      if (t < LL - 2) loadB(t + 2);     // refill: ~1 step of latency hiding
    }
  }

  // ---- epilogue ----
  for (int idx = tid; idx < MA * HH; idx += TA)
    out[(size_t)(q0 + (idx >> 7)) * HH + (idx & 127)] = sh[(idx >> 7) * SH_STR + (idx & 127)];

  if (anyf) {
    float* red = (float*)(sm + WL_OFF);   // WL dead after walk phase
    red[tid] = pAcc; red[TA + tid] = pBcc; red[2 * TA + tid] = pScc;
    __syncthreads();
    if (wv == 0) {
      float a = 0.f, b = 0.f, s = 0.f;
      for (int k2 = lane; k2 < TA; k2 += 64) {
        a += red[k2]; b += red[TA + k2]; s += red[2 * TA + k2];
      }
      #pragma unroll
      for (int off = 32; off > 0; off >>= 1) {
        a += __shfl_down(a, off); b += __shfl_down(b, off); s += __shfl_down(s, off);
      }
      if (lane == 0) {
        atomicAdd(&ws[1], a); atomicAdd(&ws[2], b); atomicAdd(&ws[3], s);
      }
    }
  }
}

__global__ void k_final(const float* __restrict__ ws, float* __restrict__ out) {
  if (threadIdx.x == 0) {
    const float cnt = (float)(SSS * SUBN * (LL - 1) * ORIGF);  // 179200
    const float pos_w = cnt / ws[3];
    const float loss = (pos_w * ws[1] + ws[2]) / cnt;
    out[NSEQ * HH] = loss;
  }
}

extern "C" void kernel_launch(void* const* d_in, const int* in_sizes, int n_in,
                              void* d_out, int out_size, void* d_ws, size_t ws_size,
                              hipStream_t stream) {
  const float* hfeat = (const float*)d_in[0];
  const float* y0    = (const float*)d_in[1];
  const float* Wih_w = (const float*)d_in[2];
  const float* Whh_w = (const float*)d_in[3];
  const float* bih_w = (const float*)d_in[4];
  const float* bhh_w = (const float*)d_in[5];
  const float* Wih   = (const float*)d_in[6];
  const float* Whh   = (const float*)d_in[7];
  const float* bih   = (const float*)d_in[8];
  const float* bhh   = (const float*)d_in[9];
  const float* W_ss  = (const float*)d_in[10];
  const float* b_ss  = (const float*)d_in[11];
  const int* walks = (const int*)d_in[12];
  const int* idxs  = (const int*)d_in[13];
  float* out = (float*)d_out;
  float* ws = (float*)d_ws;

  const bool bf = (ws_size >= WS_NEED);    // constant across calls

  (void)hipFuncSetAttribute((const void*)k_rum<true>,
                            hipFuncAttributeMaxDynamicSharedMemorySize, LDS_TOTAL);
  (void)hipFuncSetAttribute((const void*)k_rum<false>,
                            hipFuncAttributeMaxDynamicSharedMemorySize, LDS_TOTAL);

  k_zero<<<1, 64, 0, stream>>>(ws);
  k_prep<<<W_TOTAL / 256, 256, 0, stream>>>(Whh_w, Whh, Wih, ws);
  if (bf) k_prep_h<<<(NN * HH) / 256, 256, 0, stream>>>(hfeat, ws);

  const int grid = NSEQ / MA;               // 2500, exact
  if (bf)
    k_rum<true><<<grid, TA, LDS_TOTAL, stream>>>(hfeat, y0, Wih_w, bih_w, bhh_w,
                                                 bih, bhh, W_ss, b_ss,
                                                 walks, idxs, out, ws);
  else
    k_rum<false><<<grid, TA, LDS_TOTAL, stream>>>(hfeat, y0, Wih_w, bih_w, bhh_w,
                                                  bih, bhh, W_ss, b_ss,
                                                  walks, idxs, out, ws);

  k_final<<<1, 64, 0, stream>>>(ws, out);
}